// Round 9
// baseline (284.108 us; speedup 1.0000x reference)
//
#include <hip/hip_runtime.h>

#define B_ROWS 16384
#define D_IN   1024
#define KF     176      // HF k16 count: 2816/16
#define H2N    128

typedef unsigned short u16;
typedef __attribute__((ext_vector_type(4)))  float f32x4;
typedef __attribute__((ext_vector_type(16))) float f32x16;
typedef __attribute__((ext_vector_type(8)))  short s16x8;
typedef __attribute__((ext_vector_type(8)))  unsigned short u16x8;

__device__ __forceinline__ u16 f2bf(float f){
  unsigned int u = __float_as_uint(f);
  u += 0x7FFFu + ((u >> 16) & 1u);
  return (u16)(u >> 16);
}
__device__ __forceinline__ float bf2f(u16 h){
  return __uint_as_float(((unsigned int)h) << 16);
}

// ---------------- weight packing ----------------
// Fragment layout (32x32x16 MFMA, A and B identical): frag(blk32, k16):
//   lane holds [dim32 = lane&31][k = k16*16 + (lane>>5)*8 + j], 8 bf16 = 16B/lane,
//   frag line = 64 lanes x 16B = 1KB contiguous -> every load fully coalesced.

// W1F[((n32*64 + k16)*64 + lane)*8 + j];  n32 0..87, k16 0..63
__global__ void pack_w1_kernel(const float* __restrict__ sW1, const float* __restrict__ dW1,
                               const float* __restrict__ gW1, const float* __restrict__ sb1,
                               const float* __restrict__ db1, const float* __restrict__ gb1,
                               u16* __restrict__ W1F, float* __restrict__ b1c)
{
  __shared__ float t[64*65];
  const int tid = threadIdx.x;
  const int bid = blockIdx.x;          // 44 * 16
  const int ntile = bid >> 4, dtile = bid & 15;
  const int n0 = ntile*64, d0 = dtile*64;
  #pragma unroll
  for (int i=0;i<16;++i){
    int idx = i*256 + tid;
    int dd = idx >> 6, nn = idx & 63;
    int n = n0 + nn, d = d0 + dd;
    float v;
    if (n < 2560){
      int e = n >> 8, h = n & 255;
      v = (e < 4) ? sW1[((size_t)e*D_IN + d)*256 + h]
                  : dW1[((size_t)(e-4)*D_IN + d)*256 + h];
    } else if (n < 2752){
      int t2 = n - 2560; int gg = t2 >> 6, k = t2 & 63;
      v = gW1[((size_t)gg*D_IN + d)*64 + k];
    } else v = 0.f;
    t[nn*65 + dd] = v;
  }
  __syncthreads();
  #pragma unroll
  for (int i=0;i<16;++i){
    int idx = i*256 + tid;
    int nn = idx >> 6, dd = idx & 63;
    const int n = n0 + nn, d = d0 + dd;
    const int lane = ((d >> 3) & 1)*32 + (n & 31);
    const size_t di = (((size_t)(n >> 5)*64 + (d >> 4))*64 + lane)*8 + (d & 7);
    W1F[di] = f2bf(t[nn*65 + dd]);
  }
  if (dtile == 0 && tid < 64){
    int n = n0 + tid; float v;
    if (n < 2560){ int e = n>>8, h = n&255; v = (e<4)? sb1[e*256+h] : db1[(e-4)*256+h]; }
    else if (n < 2752){ int t2 = n-2560; v = gb1[(t2>>6)*64 + (t2&63)]; }
    else v = 0.f;
    b1c[n] = v;
  }
}

// W2F[(((e*4 + n32)*16 + k16)*64 + lane)*8 + j]
__global__ void pack_w2_kernel(const float* __restrict__ sW2, const float* __restrict__ dW2,
                               const float* __restrict__ sb2, const float* __restrict__ db2,
                               u16* __restrict__ W2F, float* __restrict__ b2c)
{
  const int tid = threadIdx.x;
  const int bid = blockIdx.x;          // 160 = 10 experts * 16
  const int e   = bid >> 4;
  const int sub = (bid & 15)*256 + tid;   // 0..4095
  const int n32 = sub >> 10, k16 = (sub >> 6) & 15, lane = sub & 63;
  const int c   = n32*32 + (lane & 31);
  const int kb  = k16*16 + (lane >> 5)*8;
  u16 out[8];
  #pragma unroll
  for (int j=0;j<8;++j){
    const int k = kb + j;
    float v = (e < 4) ? sW2[((size_t)e*256 + k)*128 + c]
                      : dW2[((size_t)(e-4)*256 + k)*128 + c];
    out[j] = f2bf(v);
  }
  *(u16x8*)&W2F[(size_t)e*32768 + (size_t)sub*8] = *(u16x8*)out;
  if ((bid & 15) == 0 && tid < 128)
    b2c[e*128 + tid] = (e < 4) ? sb2[e*128 + tid] : db2[(e-4)*128 + tid];
}

// XF[((r32*64 + k16)*64 + lane)*8 + j] = x[r32*32 + (lane&31)][k16*16 + (lane>>5)*8 + j]
__global__ void pack_x_kernel(const float* __restrict__ x, u16* __restrict__ XF)
{
  __shared__ float t[32*257];
  const int tid = threadIdx.x;
  const int rb  = blockIdx.x;        // 0..511  (32-row band)
  const int cb  = blockIdx.y;        // 0..3    (256-col band)
  const int row = tid >> 3;
  const int c0  = (tid & 7) * 4;
  const float* src = x + (size_t)(rb*32 + row)*D_IN + cb*256 + c0;
  #pragma unroll
  for (int i=0;i<8;++i){            // cols c0 + 32*i .. +3
    f32x4 v = *(const f32x4*)(src + i*32);
    float* d = &t[row*257 + c0 + i*32];
    d[0]=v[0]; d[1]=v[1]; d[2]=v[2]; d[3]=v[3];
  }
  __syncthreads();
  #pragma unroll
  for (int it=0; it<4; ++it){
    const int slot = it*256 + tid;   // 0..1023 = 16 k16l x 64 lanes
    const int k16l = slot >> 6;
    const int ln   = slot & 63;
    const int r    = ln & 31;
    const int kc   = k16l*16 + (ln>>5)*8;
    u16 o[8];
    #pragma unroll
    for (int j=0;j<8;++j) o[j] = f2bf(t[r*257 + kc + j]);
    *(u16x8*)&XF[(((size_t)rb*64 + cb*16 + k16l)*64 + ln)*8] = *(u16x8*)o;
  }
}

// ---------------- GEMM1: 256x256 tile, NO LDS in main loop, NO barriers ----------------
// 8 waves (2wm x 4wn), wave 128x64 = 4mf x 2nf 32x32 frags. 64 k16 steps; per step
// per wave: 6 coalesced global b128 loads (frag-packed) + 8 MFMA. Software-pipelined
// one step ahead with named reg sets (a0/b0 vs a1/b1). L1 catches 4x wave A-reuse.
// Epilogue: LDS-transpose 256x256 tile into fragment-packed HF (quarters of 64 rows).

#define G1LOAD(S, A, B) do{ \
  const size_t o_ = (size_t)(S)*512; \
  A[0] = *(const s16x8*)(pa + o_); \
  A[1] = *(const s16x8*)(pa + o_ + 32768); \
  A[2] = *(const s16x8*)(pa + o_ + 65536); \
  A[3] = *(const s16x8*)(pa + o_ + 98304); \
  B[0] = *(const s16x8*)(pb + o_); \
  B[1] = *(const s16x8*)(pb + o_ + 32768); \
}while(0)

#define G1MFMA(A, B) do{ \
  acc[0][0] = __builtin_amdgcn_mfma_f32_32x32x16_bf16(A[0], B[0], acc[0][0], 0, 0, 0); \
  acc[0][1] = __builtin_amdgcn_mfma_f32_32x32x16_bf16(A[0], B[1], acc[0][1], 0, 0, 0); \
  acc[1][0] = __builtin_amdgcn_mfma_f32_32x32x16_bf16(A[1], B[0], acc[1][0], 0, 0, 0); \
  acc[1][1] = __builtin_amdgcn_mfma_f32_32x32x16_bf16(A[1], B[1], acc[1][1], 0, 0, 0); \
  acc[2][0] = __builtin_amdgcn_mfma_f32_32x32x16_bf16(A[2], B[0], acc[2][0], 0, 0, 0); \
  acc[2][1] = __builtin_amdgcn_mfma_f32_32x32x16_bf16(A[2], B[1], acc[2][1], 0, 0, 0); \
  acc[3][0] = __builtin_amdgcn_mfma_f32_32x32x16_bf16(A[3], B[0], acc[3][0], 0, 0, 0); \
  acc[3][1] = __builtin_amdgcn_mfma_f32_32x32x16_bf16(A[3], B[1], acc[3][1], 0, 0, 0); \
}while(0)

__global__ __launch_bounds__(512, 2) void gemm1_kernel(
    const u16* __restrict__ XF, const u16* __restrict__ W1F,
    const float* __restrict__ b1c, u16* __restrict__ HF)
{
  __shared__ __attribute__((aligned(16))) u16 T[64*264];   // epilogue transpose (33.8 KB)
  const int tid  = threadIdx.x;
  const int lane = tid & 63;
  const int wid  = tid >> 6;
  const int wm   = wid >> 2;          // 0..1
  const int wn   = wid & 3;           // 0..3

  // 704 = 64 mt x 11 nt; per XCD: 8-mt band (A 4MB L2-resident), nt slow
  const int bid = blockIdx.x;
  const int xcd = bid & 7, pos = bid >> 3;
  const int mt  = xcd*8 + (pos & 7);
  const int nt  = pos >> 3;

  const int l31 = lane & 31, l5 = lane >> 5;

  const u16* pa = XF  + ((size_t)(mt*8 + wm*4)*64*64 + lane)*8;   // mf stride 32768 elems
  const u16* pb = W1F + ((size_t)(nt*8 + wn*2)*64*64 + lane)*8;   // nf stride 32768

  f32x16 acc[4][2];
  #pragma unroll
  for (int mf=0;mf<4;++mf)
    #pragma unroll
    for (int nf=0;nf<2;++nf)
      #pragma unroll
      for (int r=0;r<16;++r) acc[mf][nf][r] = 0.f;

  s16x8 a0[4], a1[4], b0[2], b1[2];

  G1LOAD(0, a0, b0);
  #pragma unroll 1
  for (int i=0; i<31; ++i){
    G1LOAD(2*i+1, a1, b1);
    G1MFMA(a0, b0);
    G1LOAD(2*i+2, a0, b0);
    G1MFMA(a1, b1);
    if ((i & 7) == 7) __builtin_amdgcn_s_barrier();   // keep waves' L1 windows aligned
  }
  G1LOAD(63, a1, b1);
  G1MFMA(a0, b0);   // s=62
  G1MFMA(a1, b1);   // s=63

  // epilogue: bias+relu, transpose via LDS in 64-row quarters, store fragment-packed HF
  #pragma unroll 1
  for (int q=0; q<4; ++q){
    if (wm == (q >> 1)){
      #pragma unroll
      for (int mfq=0; mfq<2; ++mfq){
        const int mf = (q & 1)*2 + mfq;
        #pragma unroll
        for (int nf=0; nf<2; ++nf){
          const int col = wn*64 + nf*32 + l31;
          const float bias = b1c[nt*256 + col];
          #pragma unroll
          for (int r=0;r<16;++r){
            const int rowq = mfq*32 + 4*l5 + (r&3) + 8*(r>>2);
            float v = acc[mf][nf][r] + bias;
            v = v > 0.f ? v : 0.f;
            T[rowq*264 + col] = f2bf(v);
          }
        }
      }
    }
    __syncthreads();
    #pragma unroll
    for (int it=0; it<4; ++it){
      const int slot = it*512 + tid;      // 0..2047 = 32 frags x 64 lanes
      const int fr   = slot >> 6;
      const int ln   = slot & 63;
      const int r32l = fr >> 4;           // 0..1
      const int k16l = fr & 15;
      const int row  = r32l*32 + (ln & 31);
      const int kc   = k16l*16 + (ln>>5)*8;
      const u16x8 v = *(const u16x8*)&T[row*264 + kc];
      const size_t r32g = mt*8 + q*2 + r32l;
      const size_t k16g = nt*16 + k16l;
      *(u16x8*)&HF[((r32g*KF + k16g)*64 + ln)*8] = v;
    }
    __syncthreads();
  }
}

// ---------------- gates: softmax((relu-hidden) @ gW2 + gb2), H read from HF ----------------
__global__ void gates_kernel(const u16* __restrict__ HF, const float* __restrict__ gW2,
                             const float* __restrict__ gb2, float* __restrict__ gts)
{
  __shared__ float wsm[64*6];
  __shared__ float bsm[6];
  const int tid = threadIdx.x;
  const int bid = blockIdx.x;                 // 3 * 64 blocks
  const int g = bid >> 6;
  const int b = ((bid & 63) << 8) + tid;
  if (tid < 6) bsm[tid] = gb2[g*6 + tid];
  for (int i = tid; i < 384; i += 256) wsm[i] = gW2[g*384 + i];
  __syncthreads();
  const int r32 = b >> 5, bl = b & 31;
  float lg[6];
  #pragma unroll
  for (int e=0;e<6;++e) lg[e] = bsm[e];
  #pragma unroll
  for (int kk=0; kk<4; ++kk){
    const int k16 = 160 + g*4 + kk;
    #pragma unroll
    for (int h5=0; h5<2; ++h5){
      u16x8 hv = *(const u16x8*)&HF[(((size_t)r32*KF + k16)*64 + h5*32 + bl)*8];
      #pragma unroll
      for (int j=0;j<8;++j){
        const float h = bf2f(hv[j]);
        const int k = kk*16 + h5*8 + j;
        #pragma unroll
        for (int e=0;e<6;++e) lg[e] += h * wsm[k*6 + e];
      }
    }
  }
  float mx = lg[0];
  #pragma unroll
  for (int e=1;e<6;++e) mx = fmaxf(mx, lg[e]);
  float s = 0.f; float p[6];
  #pragma unroll
  for (int e=0;e<6;++e){ p[e] = expf(lg[e]-mx); s += p[e]; }
  const float inv = 1.f / s;
  float* dst = gts + ((size_t)g*B_ROWS + b)*6;
  #pragma unroll
  for (int e=0;e<6;++e) dst[e] = p[e]*inv;
}

// ------- GEMM2: 64x128 tile, NO LDS loop, fused gate-weighted combine -------
// 4 waves, wave 64x32 (2mf x 1nf). K = 6 experts x 16 k16. Per kk: 3 loads + 2 MFMA,
// pipelined one step ahead incl. across expert boundary.

#define G2LOAD(EID, KK, A, B) do{ \
  const size_t oa_ = ((size_t)(EID)*16 + (KK))*512; \
  A[0] = *(const s16x8*)(pa2 + oa_); \
  A[1] = *(const s16x8*)(pa2 + oa_ + 90112); \
  B[0] = *(const s16x8*)(pb2 + (size_t)(EID)*32768 + (KK)*512); \
}while(0)

#define G2MFMA(A, B) do{ \
  eacc[0] = __builtin_amdgcn_mfma_f32_32x32x16_bf16(A[0], B[0], eacc[0], 0, 0, 0); \
  eacc[1] = __builtin_amdgcn_mfma_f32_32x32x16_bf16(A[1], B[0], eacc[1], 0, 0, 0); \
}while(0)

__global__ __launch_bounds__(256, 3) void gemm2_kernel(
    const u16* __restrict__ HF, const u16* __restrict__ W2F,
    const float* __restrict__ b2c, const float* __restrict__ gts,
    float* __restrict__ outp)
{
  __shared__ float gsm[64*6];
  __shared__ float bsm[6*128];
  const int tid  = threadIdx.x;
  const int lane = tid & 63;
  const int wid  = tid >> 6;          // 0..3 = column strip
  const int l31  = lane & 31, l5 = lane >> 5;

  const int bid = blockIdx.x;         // 768 = 256 mt2 * 3 g  (g fast)
  const int mt2 = bid / 3;
  const int g   = bid - mt2*3;
  const int row0 = mt2*64;

  for (int i = tid; i < 384; i += 256)
    gsm[i] = gts[((size_t)g*B_ROWS + row0)*6 + i];
  for (int i = tid; i < 768; i += 256){
    const int e_ = i >> 7;
    const int eid_ = (e_ < 4) ? e_ : (g*2 + e_);
    bsm[i] = b2c[eid_*128 + (i & 127)];
  }
  __syncthreads();

  const u16* pa2 = HF  + ((size_t)(mt2*2)*KF*64 + lane)*8;   // mf stride 90112 elems
  const u16* pb2 = W2F + ((size_t)wid*16*64 + lane)*8;       // + eid*32768 + kk*512

  f32x16 eacc[2], oacc[2];
  #pragma unroll
  for (int mf=0;mf<2;++mf)
    #pragma unroll
    for (int r=0;r<16;++r){ eacc[mf][r] = 0.f; oacc[mf][r] = 0.f; }

  s16x8 a0[2], a1[2], b0[1], b1[1];

  G2LOAD(0, 0, a0, b0);
  #pragma unroll 1
  for (int e=0; e<6; ++e){
    const int eid  = (e < 4) ? e : (g*2 + e);
    #pragma unroll
    for (int i=0; i<7; ++i){
      G2LOAD(eid, 2*i+1, a1, b1);
      G2MFMA(a0, b0);
      G2LOAD(eid, 2*i+2, a0, b0);
      G2MFMA(a1, b1);
    }
    G2LOAD(eid, 15, a1, b1);
    G2MFMA(a0, b0);                       // kk=14
    if (e < 5){
      const int eidn = (e+1 < 4) ? (e+1) : (g*2 + e+1);
      G2LOAD(eidn, 0, a0, b0);
    }
    G2MFMA(a1, b1);                       // kk=15
    // combine: oacc += gate[row] * relu(eacc + bias)
    #pragma unroll
    for (int mf=0;mf<2;++mf){
      const float bias = bsm[e*128 + wid*32 + l31];
      #pragma unroll
      for (int r=0;r<16;++r){
        const int rl = mf*32 + 4*l5 + (r&3) + 8*(r>>2);
        float v = eacc[mf][r] + bias;
        v = v > 0.f ? v : 0.f;
        oacc[mf][r] += gsm[rl*6 + e] * v;
        eacc[mf][r] = 0.f;
      }
    }
  }

  #pragma unroll
  for (int mf=0;mf<2;++mf){
    #pragma unroll
    for (int r=0;r<16;++r){
      const int rl = mf*32 + 4*l5 + (r&3) + 8*(r>>2);
      outp[((size_t)g*B_ROWS + row0 + rl)*H2N + wid*32 + l31] = oacc[mf][r];
    }
  }
}

extern "C" void kernel_launch(void* const* d_in, const int* in_sizes, int n_in,
                              void* d_out, int out_size, void* d_ws, size_t ws_size,
                              hipStream_t stream)
{
  (void)in_sizes; (void)n_in; (void)out_size; (void)ws_size;
  const float* x   = (const float*)d_in[0];
  const float* sW1 = (const float*)d_in[2];
  const float* sb1 = (const float*)d_in[3];
  const float* sW2 = (const float*)d_in[4];
  const float* sb2 = (const float*)d_in[5];
  const float* dW1 = (const float*)d_in[6];
  const float* db1 = (const float*)d_in[7];
  const float* dW2 = (const float*)d_in[8];
  const float* db2 = (const float*)d_in[9];
  const float* gW1 = (const float*)d_in[10];
  const float* gb1 = (const float*)d_in[11];
  const float* gW2 = (const float*)d_in[12];
  const float* gb2 = (const float*)d_in[13];
  float* outp = (float*)d_out;

  char* ws = (char*)d_ws;
  u16*   XF  = (u16*  )(ws + 0);          // 16384*1024*2      = 33554432
  u16*   W1F = (u16*  )(ws + 33554432);   // 88*64*64*8*2      =  5767168
  float* b1c = (float*)(ws + 39321600);   // 2816*4            =    11264
  u16*   W2F = (u16*  )(ws + 39332864);   // 10*4*16*64*8*2    =   655360
  float* b2c = (float*)(ws + 39988224);   // 10*128*4          =     5120
  float* gts = (float*)(ws + 39993344);   // 3*16384*6*4       =  1179648
  u16*   HF  = (u16*  )(ws + 41172992);   // 512*176*512*2     = 92274688  (end ~133.4 MB)

  pack_w1_kernel<<<dim3(704),     dim3(256), 0, stream>>>(sW1,dW1,gW1,sb1,db1,gb1,W1F,b1c);
  pack_w2_kernel<<<dim3(160),     dim3(256), 0, stream>>>(sW2,dW2,sb2,db2,W2F,b2c);
  pack_x_kernel <<<dim3(512,4),   dim3(256), 0, stream>>>(x, XF);
  gemm1_kernel  <<<dim3(704),     dim3(512), 0, stream>>>(XF, W1F, b1c, HF);
  gates_kernel  <<<dim3(192),     dim3(256), 0, stream>>>(HF, gW2, gb2, gts);
  gemm2_kernel  <<<dim3(768),     dim3(256), 0, stream>>>(HF, W2F, b2c, gts, outp);
}

// Round 10
// 158.038 us; speedup vs baseline: 1.7977x; 1.7977x over previous
//
#include <hip/hip_runtime.h>

#define B_ROWS 16384
#define D_IN   1024
#define NW1P   2816   // padded GEMM1 N: 10*256 expert + 3*64 gate + 64 pad
#define H2N    128

typedef unsigned short u16;
typedef __attribute__((ext_vector_type(4)))  float f32x4;
typedef __attribute__((ext_vector_type(16))) float f32x16;
typedef __attribute__((ext_vector_type(8)))  short s16x8;
typedef __attribute__((ext_vector_type(8)))  unsigned short u16x8;

__device__ __forceinline__ u16 f2bf(float f){
  unsigned int u = __float_as_uint(f);
  u += 0x7FFFu + ((u >> 16) & 1u);
  return (u16)(u >> 16);
}
__device__ __forceinline__ float bf2f(u16 h){
  return __uint_as_float(((unsigned int)h) << 16);
}

// async global->LDS, 16B per lane. LDS dest must be linear (wave base + lane*16).
__device__ __forceinline__ void gload_lds16(const void* gp, void* lp){
  typedef __attribute__((address_space(1))) unsigned int GUI;
  typedef __attribute__((address_space(3))) unsigned int LUI;
  __builtin_amdgcn_global_load_lds((GUI*)(unsigned long long)gp,
                                   (LUI*)(unsigned int)(unsigned long long)lp,
                                   16, 0, 0);
}

// ---------------- weight packing ----------------
// W1T[n][d] row-major (r2-verified)
__global__ void pack_w1_kernel(const float* __restrict__ sW1, const float* __restrict__ dW1,
                               const float* __restrict__ gW1, const float* __restrict__ sb1,
                               const float* __restrict__ db1, const float* __restrict__ gb1,
                               u16* __restrict__ W1T, float* __restrict__ b1c)
{
  __shared__ float t[64*65];
  const int tid = threadIdx.x;
  const int bid = blockIdx.x;          // 44 * 16
  const int ntile = bid >> 4, dtile = bid & 15;
  const int n0 = ntile*64, d0 = dtile*64;
  #pragma unroll
  for (int i=0;i<16;++i){
    int idx = i*256 + tid;
    int dd = idx >> 6, nn = idx & 63;
    int n = n0 + nn, d = d0 + dd;
    float v;
    if (n < 2560){
      int e = n >> 8, h = n & 255;
      v = (e < 4) ? sW1[((size_t)e*D_IN + d)*256 + h]
                  : dW1[((size_t)(e-4)*D_IN + d)*256 + h];
    } else if (n < 2752){
      int t2 = n - 2560; int gg = t2 >> 6, k = t2 & 63;
      v = gW1[((size_t)gg*D_IN + d)*64 + k];
    } else v = 0.f;
    t[nn*65 + dd] = v;
  }
  __syncthreads();
  #pragma unroll
  for (int i=0;i<16;++i){
    int idx = i*256 + tid;
    int nn = idx >> 6, dd = idx & 63;
    W1T[(size_t)(n0+nn)*D_IN + d0 + dd] = f2bf(t[nn*65 + dd]);
  }
  if (dtile == 0 && tid < 64){
    int n = n0 + tid; float v;
    if (n < 2560){ int e = n>>8, h = n&255; v = (e<4)? sb1[e*256+h] : db1[(e-4)*256+h]; }
    else if (n < 2752){ int t2 = n-2560; v = gb1[(t2>>6)*64 + (t2&63)]; }
    else v = 0.f;
    b1c[n] = v;
  }
}

// W2F: fragment-packed W2 for 32x32x16 B operand (r8-verified).
__global__ void pack_w2_kernel(const float* __restrict__ sW2, const float* __restrict__ dW2,
                               const float* __restrict__ sb2, const float* __restrict__ db2,
                               u16* __restrict__ W2F, float* __restrict__ b2c)
{
  const int tid = threadIdx.x;
  const int bid = blockIdx.x;          // 160 = 10 experts * 16
  const int e   = bid >> 4;
  const int sub = (bid & 15)*256 + tid;   // 0..4095
  const int n32 = sub >> 10, k16 = (sub >> 6) & 15, lane = sub & 63;
  const int c   = n32*32 + (lane & 31);
  const int kb  = k16*16 + (lane >> 5)*8;
  u16 out[8];
  #pragma unroll
  for (int j=0;j<8;++j){
    const int k = kb + j;
    float v = (e < 4) ? sW2[((size_t)e*256 + k)*128 + c]
                      : dW2[((size_t)(e-4)*256 + k)*128 + c];
    out[j] = f2bf(v);
  }
  *(u16x8*)&W2F[(size_t)e*32768 + (size_t)sub*8] = *(u16x8*)out;
  if ((bid & 15) == 0 && tid < 128)
    b2c[e*128 + tid] = (e < 4) ? sb2[e*128 + tid] : db2[(e-4)*128 + tid];
}

__global__ void cast_x_kernel(const float* __restrict__ x, u16* __restrict__ xb)
{
  const size_t i = ((size_t)blockIdx.x*256 + threadIdx.x)*8;
  f32x4 a = *(const f32x4*)(x + i);
  f32x4 b = *(const f32x4*)(x + i + 4);
  u16x8 r;
  r[0]=f2bf(a[0]); r[1]=f2bf(a[1]); r[2]=f2bf(a[2]); r[3]=f2bf(a[3]);
  r[4]=f2bf(b[0]); r[5]=f2bf(b[1]); r[6]=f2bf(b[2]); r[7]=f2bf(b[3]);
  *(u16x8*)(xb + i) = r;
}

// ---------------- GEMM1: m201-faithful 8-phase, 256x256, BK=64, 16x16x32 ----------------
// 8 waves (2wm x 4wn), wave 128x64 = 8x4 16x16 frags, acc split in 2x2 quadrants.
// Per K-tile, 4 phases (m0n0),(m0n1),(m1n0),(m1n1): reads 12/4/8/0 ds_read_b128;
// each phase {reads | stage | BAR | lgkm0 | setprio1 16xMFMA setprio0 | BAR}.
// Stage t+1: A-halves at ph0, B-halves at ph1 (2 gloads/thread each);
// waits: vmcnt(4) end-ph2 (counted: B still in flight), vmcnt(0) end-ph3 (2-phase slack).
// XOR slot swizzle phys = slot ^ (row&7), both sides (0 conflicts, r2-verified).

#define BAR  __builtin_amdgcn_s_barrier()
#define LG0  asm volatile("s_waitcnt lgkmcnt(0)" ::: "memory")
#define LG8  asm volatile("s_waitcnt lgkmcnt(8)" ::: "memory")
#define VMW(N) asm volatile("s_waitcnt vmcnt(" #N ")" ::: "memory")

#define SGHA(T, P, H) do{ \
  gload_lds16(aStg + (T)*64 + (size_t)((H)*128     )*D_IN, &L[(P)*16384 + (H)*8192 + tid*8]); \
  gload_lds16(aStg + (T)*64 + (size_t)((H)*128 + 64)*D_IN, &L[(P)*16384 + (H)*8192 + 4096 + tid*8]); \
}while(0)
#define SGHB(T, P, H) do{ \
  gload_lds16(bStg + (T)*64 + (size_t)((H)*128     )*D_IN, &L[32768 + (P)*16384 + (H)*8192 + tid*8]); \
  gload_lds16(bStg + (T)*64 + (size_t)((H)*128 + 64)*D_IN, &L[32768 + (P)*16384 + (H)*8192 + 4096 + tid*8]); \
}while(0)

#define LDAQ(P, MQ) do{ \
  _Pragma("unroll") for (int mf=0;mf<4;++mf){ \
    const int rb_ = ((P)*16384) + (wm*128 + (MQ)*64 + mf*16 + fr)*64; \
    aq[mf][0] = *(const s16x8*)&L[rb_ + o0]; \
    aq[mf][1] = *(const s16x8*)&L[rb_ + o1]; } \
}while(0)
#define LDBQ(P, NQ, BQ) do{ \
  _Pragma("unroll") for (int nf=0;nf<2;++nf){ \
    const int rb_ = (32768 + (P)*16384) + (wn*64 + (NQ)*32 + nf*16 + fr)*64; \
    BQ[nf][0] = *(const s16x8*)&L[rb_ + o0]; \
    BQ[nf][1] = *(const s16x8*)&L[rb_ + o1]; } \
}while(0)

#define MFQ(MQ, NQ, BQ) do{ \
  __builtin_amdgcn_s_setprio(1); \
  _Pragma("unroll") for (int mf=0;mf<4;++mf) \
    _Pragma("unroll") for (int nf=0;nf<2;++nf){ \
      acc[(MQ)*4+mf][(NQ)*2+nf] = __builtin_amdgcn_mfma_f32_16x16x32_bf16(aq[mf][0], BQ[nf][0], acc[(MQ)*4+mf][(NQ)*2+nf],0,0,0); \
      acc[(MQ)*4+mf][(NQ)*2+nf] = __builtin_amdgcn_mfma_f32_16x16x32_bf16(aq[mf][1], BQ[nf][1], acc[(MQ)*4+mf][(NQ)*2+nf],0,0,0); } \
  __builtin_amdgcn_s_setprio(0); \
}while(0)

#define KTILE(P, Q, T1, ST) do{ \
  /* ph0: quad(m0,n0), 12 reads; stage A(t+1) */ \
  LDAQ(P, 0); LDBQ(P, 0, bq0); \
  if (ST){ SGHA(T1, Q, 0); SGHA(T1, Q, 1); } \
  LG8; BAR; LG0; MFQ(0,0,bq0); BAR; \
  /* ph1: quad(m0,n1), 4 reads; stage B(t+1) */ \
  LDBQ(P, 1, bq1); \
  if (ST){ SGHB(T1, Q, 0); SGHB(T1, Q, 1); } \
  BAR; LG0; MFQ(0,1,bq1); BAR; \
  /* ph2: quad(m1,n0), 8 reads; counted wait on A-stage */ \
  LDAQ(P, 1); \
  BAR; LG0; MFQ(1,0,bq0); VMW(4); BAR; \
  /* ph3: quad(m1,n1), 0 reads; drain B-stage (2-phase slack) */ \
  MFQ(1,1,bq1); VMW(0); BAR; \
}while(0)

__global__ __launch_bounds__(512, 2) void gemm1_kernel(
    const u16* __restrict__ Xb, const u16* __restrict__ W1T,
    const float* __restrict__ b1c, u16* __restrict__ Hb)
{
  // A: buf p at p*16384; B: 32768 + p*16384 (u16 elems). 128 KiB total.
  __shared__ __attribute__((aligned(16))) u16 L[65536];
  const int tid  = threadIdx.x;
  const int lane = tid & 63;
  const int wid  = tid >> 6;
  const int wm   = wid >> 2;          // 0..1
  const int wn   = wid & 3;           // 0..3

  // 704 = 64 mt x 11 nt; per XCD mt-fast (FETCH ~71MB verified r7/r8)
  const int bid = blockIdx.x;
  const int xcd = bid & 7, pos = bid >> 3;
  const int mt  = xcd*8 + (pos & 7);
  const int nt  = pos >> 3;
  const int row0 = mt*256, col0 = nt*256;

  const int fr = lane & 15;           // fragment row
  const int kq = lane >> 4;           // k quarter 0..3
  const int l7 = fr & 7;
  const int o0 = ((kq     ^ l7) << 3);  // ks=0 slot, swizzled, in elems
  const int o1 = (((4+kq) ^ l7) << 3);  // ks=1

  // staging: thread -> row (tid>>3)(+64j+128H), phys slot (tid&7); pre-swizzled src
  const int sSl = (tid & 7) ^ ((tid >> 3) & 7);
  const u16* aStg = Xb  + (size_t)(row0 + (tid>>3))*D_IN + sSl*8;
  const u16* bStg = W1T + (size_t)(col0 + (tid>>3))*D_IN + sSl*8;

  f32x4 acc[8][4];
  const f32x4 fz = {0.f,0.f,0.f,0.f};
  #pragma unroll
  for (int m=0;m<8;++m)
    #pragma unroll
    for (int n=0;n<4;++n) acc[m][n] = fz;

  s16x8 aq[4][2], bq0[2][2], bq1[2][2];

  // prologue: stage tile 0 fully into buf 0
  SGHA(0, 0, 0); SGHA(0, 0, 1);
  SGHB(0, 0, 0); SGHB(0, 0, 1);
  VMW(0); BAR;

  #pragma unroll 1
  for (int it=0; it<8; ++it){
    const int T = 2*it;
    KTILE(0, 1, T+1, 1);
    KTILE(1, 0, T+2, (it<7));
  }

  // epilogue: bias + relu + bf16 store. C/D: col=lane&15, row=(lane>>4)*4+r
  const int r4 = kq << 2;
  #pragma unroll
  for (int m=0;m<8;++m){
    const int gr = row0 + wm*128 + (m>>2)*64 + (m&3)*16 + r4;
    #pragma unroll
    for (int n=0;n<4;++n){
      const int gc = col0 + wn*64 + (n>>1)*32 + (n&1)*16 + fr;
      const float bias = b1c[gc];
      #pragma unroll
      for (int r=0;r<4;++r){
        float v = acc[m][n][r] + bias;
        v = v > 0.f ? v : 0.f;
        Hb[(size_t)(gr + r)*NW1P + gc] = f2bf(v);
      }
    }
  }
}

// ---------------- gates: softmax((relu-hidden) @ gW2 + gb2) ----------------
__global__ void gates_kernel(const u16* __restrict__ Hb, const float* __restrict__ gW2,
                             const float* __restrict__ gb2, float* __restrict__ gts)
{
  __shared__ float wsm[64*6];
  __shared__ float bsm[6];
  const int tid = threadIdx.x;
  const int bid = blockIdx.x;                 // 3 * 64 blocks
  const int g = bid >> 6;
  const int b = ((bid & 63) << 8) + tid;
  if (tid < 6) bsm[tid] = gb2[g*6 + tid];
  for (int i = tid; i < 384; i += 256) wsm[i] = gW2[g*384 + i];
  __syncthreads();
  const u16* gh = Hb + (size_t)b*NW1P + 2560 + g*64;
  float lg[6];
  #pragma unroll
  for (int e=0;e<6;++e) lg[e] = bsm[e];
  #pragma unroll
  for (int k8=0;k8<8;++k8){
    u16x8 hv = *(const u16x8*)&gh[k8*8];
    #pragma unroll
    for (int j=0;j<8;++j){
      const float h = bf2f(hv[j]);
      const int k = k8*8 + j;
      #pragma unroll
      for (int e=0;e<6;++e) lg[e] += h * wsm[k*6 + e];
    }
  }
  float mx = lg[0];
  #pragma unroll
  for (int e=1;e<6;++e) mx = fmaxf(mx, lg[e]);
  float s = 0.f; float p[6];
  #pragma unroll
  for (int e=0;e<6;++e){ p[e] = expf(lg[e]-mx); s += p[e]; }
  const float inv = 1.f / s;
  float* dst = gts + ((size_t)g*B_ROWS + b)*6;
  #pragma unroll
  for (int e=0;e<6;++e) dst[e] = p[e]*inv;
}

// ------- GEMM2 (r8-verified): 64x128 block, A=Hb via LDS dbuf, B=W2F frags in regs -------
#define SGA2(S, BUF) do{ \
  const int e_  = (S) >> 2; \
  const int eid_= (e_ < 4) ? e_ : (g*2 + e_); \
  const u16* ga_ = Hb + (size_t)(row0 + (tid>>3))*NW1P + eid_*256 + ((S)&3)*64 + sSl2*8; \
  gload_lds16(ga_,                     &LA[BUF][tid*8]); \
  gload_lds16(ga_ + (size_t)32*NW1P,   &LA[BUF][2048 + tid*8]); \
}while(0)

#define LOADB2(S, BV) do{ \
  const int e_  = (S) >> 2; \
  const int eid_= (e_ < 4) ? e_ : (g*2 + e_); \
  const size_t base_ = ((size_t)(eid_*4 + wn)*16 + ((S)&3)*4)*512; \
  _Pragma("unroll") for (int kk=0;kk<4;++kk) \
    BV[kk] = *(const s16x8*)(pB2 + base_ + kk*512); \
}while(0)

#define COMPUTE2(BUF, BV) do{ \
  _Pragma("unroll") for (int kk=0;kk<4;++kk){ \
    s16x8 av[2]; \
    _Pragma("unroll") for (int mf=0;mf<2;++mf){ \
      const int row_ = mf*32 + l31; \
      av[mf] = *(const s16x8*)&LA[BUF][(row_<<6) + (((((kk<<1)|l5)) ^ (row_&7))<<3)]; \
    } \
    __builtin_amdgcn_s_setprio(1); \
    eacc[0] = __builtin_amdgcn_mfma_f32_32x32x16_bf16(av[0], BV[kk], eacc[0], 0, 0, 0); \
    eacc[1] = __builtin_amdgcn_mfma_f32_32x32x16_bf16(av[1], BV[kk], eacc[1], 0, 0, 0); \
    __builtin_amdgcn_s_setprio(0); \
  } \
}while(0)

#define EPI2(E) do{ \
  const float bias_ = bsm[(E)*128 + wn*32 + l31]; \
  _Pragma("unroll") for (int mf=0;mf<2;++mf){ \
    _Pragma("unroll") for (int r=0;r<16;++r){ \
      const int rl_ = mf*32 + 4*l5 + (r&3) + 8*(r>>2); \
      float v = eacc[mf][r] + bias_; \
      v = v > 0.f ? v : 0.f; \
      oacc[mf][r] += gsm[rl_*6 + (E)] * v; \
      eacc[mf][r] = 0.f; \
    } \
  } \
}while(0)

__global__ __launch_bounds__(256, 2) void gemm2_kernel(
    const u16* __restrict__ Hb, const u16* __restrict__ W2F,
    const float* __restrict__ b2c, const float* __restrict__ gts,
    float* __restrict__ outp)
{
  __shared__ __attribute__((aligned(16))) u16 LA[2][4096];  // 2 x 8 KB (64 rows x 64 k)
  __shared__ float gsm[64*6];
  __shared__ float bsm[6*128];
  const int tid  = threadIdx.x;
  const int lane = tid & 63;
  const int wn   = tid >> 6;          // 0..3
  const int l31  = lane & 31, l5 = lane >> 5;

  const int bid = blockIdx.x;         // 768 = 256 mt * 3 g
  const int mt  = bid / 3;
  const int g   = bid - mt*3;
  const int row0 = mt*64;

  const int sSl2 = (tid & 7) ^ ((tid >> 3) & 7);
  const u16* pB2 = W2F + lane*8;

  for (int i = tid; i < 384; i += 256)
    gsm[i] = gts[((size_t)g*B_ROWS + row0)*6 + i];
  for (int i = tid; i < 768; i += 256){
    const int e_ = i >> 7;
    const int eid_ = (e_ < 4) ? e_ : (g*2 + e_);
    bsm[i] = b2c[eid_*128 + (i & 127)];
  }

  f32x16 eacc[2], oacc[2];
  #pragma unroll
  for (int mf=0;mf<2;++mf)
    #pragma unroll
    for (int r=0;r<16;++r){ eacc[mf][r] = 0.f; oacc[mf][r] = 0.f; }

  s16x8 bvA[4], bvB[4];

  SGA2(0, 0);
  LOADB2(0, bvA);
  VMW(0); BAR;

  #pragma unroll 1
  for (int i=0; i<12; ++i){
    const int s = 2*i;
    SGA2(s+1, 1);                 // 2 gld_lds
    LOADB2(s+1, bvB);             // 4 b128
    COMPUTE2(0, bvA);
    VMW(4); BAR;                  // waits the 2 gld_lds only
    if (i < 11){ SGA2(s+2, 0); LOADB2(s+2, bvA); }
    COMPUTE2(1, bvB);
    if (((s+1) & 3) == 3) EPI2((s+1) >> 2);
    VMW(4); BAR;
  }

  // store: out[g][row0+rl][wn*32+l31]
  #pragma unroll
  for (int mf=0;mf<2;++mf){
    #pragma unroll
    for (int r=0;r<16;++r){
      const int rl = mf*32 + 4*l5 + (r&3) + 8*(r>>2);
      outp[((size_t)g*B_ROWS + row0 + rl)*H2N + wn*32 + l31] = oacc[mf][r];
    }
  }
}

extern "C" void kernel_launch(void* const* d_in, const int* in_sizes, int n_in,
                              void* d_out, int out_size, void* d_ws, size_t ws_size,
                              hipStream_t stream)
{
  (void)in_sizes; (void)n_in; (void)out_size; (void)ws_size;
  const float* x   = (const float*)d_in[0];
  const float* sW1 = (const float*)d_in[2];
  const float* sb1 = (const float*)d_in[3];
  const float* sW2 = (const float*)d_in[4];
  const float* sb2 = (const float*)d_in[5];
  const float* dW1 = (const float*)d_in[6];
  const float* db1 = (const float*)d_in[7];
  const float* dW2 = (const float*)d_in[8];
  const float* db2 = (const float*)d_in[9];
  const float* gW1 = (const float*)d_in[10];
  const float* gb1 = (const float*)d_in[11];
  const float* gW2 = (const float*)d_in[12];
  const float* gb2 = (const float*)d_in[13];
  float* outp = (float*)d_out;

  char* ws = (char*)d_ws;
  u16*   Xb  = (u16*  )(ws + 0);          // 16384*1024*2      = 33554432
  u16*   W1T = (u16*  )(ws + 33554432);   // 2816*1024*2       =  5767168
  float* b1c = (float*)(ws + 39321600);   // 2816*4            =    11264
  u16*   W2F = (u16*  )(ws + 39332864);   // 10*4*16*64*8*2    =   655360
  float* b2c = (float*)(ws + 39988224);   // 10*128*4          =     5120
  float* gts = (float*)(ws + 39993344);   // 3*16384*6*4       =  1179648
  u16*   Hb  = (u16*  )(ws + 41172992);   // 16384*2816*2      = 92274688  (end ~133.4 MB)

  pack_w1_kernel<<<dim3(704),  dim3(256), 0, stream>>>(sW1,dW1,gW1,sb1,db1,gb1,W1T,b1c);
  pack_w2_kernel<<<dim3(160),  dim3(256), 0, stream>>>(sW2,dW2,sb2,db2,W2F,b2c);
  cast_x_kernel <<<dim3(8192), dim3(256), 0, stream>>>(x, Xb);
  gemm1_kernel  <<<dim3(704),  dim3(512), 0, stream>>>(Xb, W1T, b1c, Hb);
  gates_kernel  <<<dim3(192),  dim3(256), 0, stream>>>(Hb, gW2, gb2, gts);
  gemm2_kernel  <<<dim3(768),  dim3(256), 0, stream>>>(Hb, W2F, b2c, gts, outp);
}